// Round 4
// baseline (5622.403 us; speedup 1.0000x reference)
//
#include <hip/hip_runtime.h>
#include <stdint.h>

#define N_NODES 100000

// ---------------------------------------------------------------- CSR build
__global__ void zero_u32(uint32_t* p, int n){
    int i = blockIdx.x * 256 + threadIdx.x;
    if (i < n) p[i] = 0u;
}

__global__ void count_dst(const int* __restrict__ dst, uint32_t* __restrict__ cnt, int E){
    int e = blockIdx.x * 256 + threadIdx.x;
    if (e < E) atomicAdd((unsigned int*)&cnt[dst[e]], 1u);
}

// block-level scan over 1024 elements (Hillis-Steele in LDS).
__global__ void scan_blocks(const uint32_t* __restrict__ in, uint32_t* __restrict__ out,
                            uint32_t* __restrict__ bsum, int n){
    __shared__ uint32_t tmp[1024];
    int base = blockIdx.x * 1024;
    for (int j = threadIdx.x; j < 1024; j += 256)
        tmp[j] = (base + j < n) ? in[base + j] : 0u;
    __syncthreads();
    for (int off = 1; off < 1024; off <<= 1){
        uint32_t v[4];
        for (int j = 0; j < 4; j++){
            int i = threadIdx.x + j * 256;
            v[j] = (i >= off) ? tmp[i - off] : 0u;
        }
        __syncthreads();
        for (int j = 0; j < 4; j++){
            int i = threadIdx.x + j * 256;
            tmp[i] += v[j];
        }
        __syncthreads();
    }
    for (int j = threadIdx.x; j < 1024; j += 256)
        if (base + j < n) out[base + j] = (j > 0) ? tmp[j - 1] : 0u;
    if (threadIdx.x == 0) bsum[blockIdx.x] = tmp[1023];
}

// add block offsets to the scan AND compute dinv (fused: both read per-node arrays)
__global__ void add_boff_dinv(uint32_t* __restrict__ out, const uint32_t* __restrict__ boff,
                              const uint32_t* __restrict__ cnt, float* __restrict__ dinv, int n){
    int base = blockIdx.x * 1024;
    uint32_t add = boff[blockIdx.x];
    for (int j = threadIdx.x; j < 1024; j += 256){
        int i = base + j;
        if (i < n){
            out[i] += add;
            dinv[i] = rsqrtf((float)(cnt[i] + 1u));   // +1 self-loop; always > 0
        }
    }
}

__global__ void fill_csr(const int* __restrict__ src, const int* __restrict__ dst,
                         const uint32_t* __restrict__ off, uint32_t* __restrict__ cur,
                         uint32_t* __restrict__ slot, int E){
    int e = blockIdx.x * 256 + threadIdx.x;
    if (e < E){
        int d = dst[e];
        uint32_t p = atomicAdd((unsigned int*)&cur[d], 1u);
        slot[off[d] + p] = (uint32_t)src[e];
    }
}

// ---------------------------------------------------------------- aggregation (device helper)
// Pull-CSR aggregate of 8 nodes per wave into swizzled LDS tile xT.
// xT word(k,r) = k*32 + 4*((r>>2)^((k>>2)&7)) + (r&3)  -- write 8-way max, reads conflict-free.
__device__ __forceinline__ void aggregate_tile(const float* __restrict__ X,
        const uint32_t* __restrict__ offs, const uint32_t* __restrict__ cnt,
        const uint32_t* __restrict__ slot, const float* __restrict__ dinv,
        float* __restrict__ xT, int r0, int tid){
    int wid = tid >> 6, lane = tid & 63;
    const float2* X2 = (const float2*)X;
    for (int i = 0; i < 8; i++){
        int r = wid * 8 + i;
        int g = r0 + r;
        uint32_t o = offs[g], c = cnt[g];
        float accx = 0.f, accy = 0.f;
        uint32_t e = 0;
        // 4x unrolled: 4 independent load chains in flight (MLP)
        for (; e + 4 <= c; e += 4){
            uint32_t s0 = slot[o + e + 0], s1 = slot[o + e + 1];
            uint32_t s2 = slot[o + e + 2], s3 = slot[o + e + 3];
            float d0 = dinv[s0], d1 = dinv[s1], d2 = dinv[s2], d3 = dinv[s3];
            float2 v0 = X2[(size_t)s0 * 64 + lane];
            float2 v1 = X2[(size_t)s1 * 64 + lane];
            float2 v2 = X2[(size_t)s2 * 64 + lane];
            float2 v3 = X2[(size_t)s3 * 64 + lane];
            accx += d0 * v0.x + d1 * v1.x + d2 * v2.x + d3 * v3.x;
            accy += d0 * v0.y + d1 * v1.y + d2 * v2.y + d3 * v3.y;
        }
        for (; e < c; e++){
            uint32_t s = slot[o + e];
            float ds = dinv[s];
            float2 v = X2[(size_t)s * 64 + lane];
            accx += ds * v.x;
            accy += ds * v.y;
        }
        float dd = dinv[g];
        float2 self = X2[(size_t)g * 64 + lane];
        float ax = dd * (accx + dd * self.x);
        float ay = dd * (accy + dd * self.y);
        int sw = (((r >> 2) ^ ((lane >> 1) & 7)) << 2) + (r & 3);   // mask = (k>>2)&7 for k=2*lane{,+1}
        xT[(2 * lane + 0) * 32 + sw] = ax;
        xT[(2 * lane + 1) * 32 + sw] = ay;
    }
}

// ---------------------------------------------------------------- fused layer 1
// out = relu( (A_hat x) @ W1 + b1 ), 32 nodes/block, 256 threads, LDS = 32 KiB.
__global__ __launch_bounds__(256, 4) void fused_layer1(const float* __restrict__ X,
        const uint32_t* __restrict__ offs, const uint32_t* __restrict__ cnt,
        const uint32_t* __restrict__ slot, const float* __restrict__ dinv,
        const float* __restrict__ W, const float* __restrict__ bias,
        float* __restrict__ OUT){
    __shared__ float Wl[32 * 128];    // 16 KiB (one 32-row K-chunk of W)
    __shared__ float xT[128 * 32];    // 16 KiB, swizzled [k][r]
    int tid = threadIdx.x;
    int r0 = blockIdx.x * 32;

    aggregate_tile(X, offs, cnt, slot, dinv, xT, r0, tid);

    const float4* W4 = (const float4*)W;    // [128][128] row-major -> 32 float4/row
    float4* Wl4 = (float4*)Wl;
    const float4* xT4 = (const float4*)xT;
    int cg = tid & 31, rg = tid >> 5;
    float4 acc0 = {0,0,0,0}, acc1 = {0,0,0,0}, acc2 = {0,0,0,0}, acc3 = {0,0,0,0};

    #pragma unroll
    for (int chunk = 0; chunk < 4; chunk++){
        __syncthreads();                    // xT ready (1st) / prev chunk consumed (rest)
        for (int j = tid; j < 1024; j += 256) Wl4[j] = W4[chunk * 1024 + j];
        __syncthreads();
        #pragma unroll
        for (int kk = 0; kk < 32; kk++){
            int k = chunk * 32 + kk;
            float4 w  = Wl4[kk * 32 + cg];
            float4 xv = xT4[k * 8 + (rg ^ ((k >> 2) & 7))];   // mask compile-time (unrolled)
            acc0.x += xv.x * w.x; acc0.y += xv.x * w.y; acc0.z += xv.x * w.z; acc0.w += xv.x * w.w;
            acc1.x += xv.y * w.x; acc1.y += xv.y * w.y; acc1.z += xv.y * w.z; acc1.w += xv.y * w.w;
            acc2.x += xv.z * w.x; acc2.y += xv.z * w.y; acc2.z += xv.z * w.z; acc2.w += xv.z * w.w;
            acc3.x += xv.w * w.x; acc3.y += xv.w * w.y; acc3.z += xv.w * w.z; acc3.w += xv.w * w.w;
        }
    }

    float4 b = ((const float4*)bias)[cg];
    float4* O4 = (float4*)OUT;
    int rowbase = r0 + rg * 4;
    float4 o0 = {fmaxf(acc0.x + b.x, 0.f), fmaxf(acc0.y + b.y, 0.f), fmaxf(acc0.z + b.z, 0.f), fmaxf(acc0.w + b.w, 0.f)};
    float4 o1 = {fmaxf(acc1.x + b.x, 0.f), fmaxf(acc1.y + b.y, 0.f), fmaxf(acc1.z + b.z, 0.f), fmaxf(acc1.w + b.w, 0.f)};
    float4 o2 = {fmaxf(acc2.x + b.x, 0.f), fmaxf(acc2.y + b.y, 0.f), fmaxf(acc2.z + b.z, 0.f), fmaxf(acc2.w + b.w, 0.f)};
    float4 o3 = {fmaxf(acc3.x + b.x, 0.f), fmaxf(acc3.y + b.y, 0.f), fmaxf(acc3.z + b.z, 0.f), fmaxf(acc3.w + b.w, 0.f)};
    O4[(size_t)(rowbase + 0) * 32 + cg] = o0;
    O4[(size_t)(rowbase + 1) * 32 + cg] = o1;
    O4[(size_t)(rowbase + 2) * 32 + cg] = o2;
    O4[(size_t)(rowbase + 3) * 32 + cg] = o3;
}

// ---------------------------------------------------------------- fused layer 2
// out = (A_hat h1) @ W2 + b2, 32 nodes/block, 256 threads, LDS = 26 KiB.
__global__ __launch_bounds__(256, 4) void fused_layer2(const float* __restrict__ H,
        const uint32_t* __restrict__ offs, const uint32_t* __restrict__ cnt,
        const uint32_t* __restrict__ slot, const float* __restrict__ dinv,
        const float* __restrict__ W, const float* __restrict__ bias,
        float* __restrict__ OUT){
    __shared__ float Wl[64 * 40];     // 10 KiB (one 64-row K-chunk of W2)
    __shared__ float xT[128 * 32];    // 16 KiB, swizzled [k][r]
    int tid = threadIdx.x;
    int r0 = blockIdx.x * 32;

    aggregate_tile(H, offs, cnt, slot, dinv, xT, r0, tid);

    const float4* W4 = (const float4*)W;   // [128][40] -> 10 float4/row
    float4* Wl4 = (float4*)Wl;
    int r = tid >> 3, cw = tid & 7;        // 32 rows x 8 col-groups (5 cols each)
    int rhi = r >> 2, rlo = r & 3;
    float acc[5] = {0.f, 0.f, 0.f, 0.f, 0.f};

    #pragma unroll
    for (int chunk = 0; chunk < 2; chunk++){
        __syncthreads();
        for (int j = tid; j < 640; j += 256) Wl4[j] = W4[chunk * 640 + j];
        __syncthreads();
        #pragma unroll
        for (int kk = 0; kk < 64; kk++){
            int k = chunk * 64 + kk;
            float xv = xT[k * 32 + (((rhi ^ ((k >> 2) & 7)) << 2) + rlo)];
            #pragma unroll
            for (int j = 0; j < 5; j++)
                acc[j] += xv * Wl[kk * 40 + 5 * cw + j];
        }
    }
    int g = r0 + r;
    #pragma unroll
    for (int j = 0; j < 5; j++)
        OUT[(size_t)g * 40 + 5 * cw + j] = acc[j] + bias[5 * cw + j];
}

// ---------------------------------------------------------------- launch
extern "C" void kernel_launch(void* const* d_in, const int* in_sizes, int n_in,
                              void* d_out, int out_size, void* d_ws, size_t ws_size,
                              hipStream_t stream) {
    const float* x   = (const float*)d_in[0];
    const int*   ei  = (const int*)d_in[1];      // int32 (harness converts integer inputs)
    const float* W1  = (const float*)d_in[2];
    const float* b1  = (const float*)d_in[3];
    const float* W2  = (const float*)d_in[4];
    const float* b2  = (const float*)d_in[5];
    float*       out = (float*)d_out;

    const int N = N_NODES;
    const int E = in_sizes[1] / 2;
    const int* src = ei;
    const int* dst = ei + E;

    // workspace carve-up (512B-aligned). cnt/offs/cur are contiguous -> one zeroing pass.
    char* ws = (char*)d_ws;
    size_t o = 0;
    auto alloc = [&](size_t bytes) -> char* {
        char* p = ws + o;
        o += (bytes + 511) & ~(size_t)511;
        return p;
    };
    uint32_t* cnt   = (uint32_t*)alloc((size_t)N * 4);
    uint32_t* offs  = (uint32_t*)alloc((size_t)N * 4);
    uint32_t* cur   = (uint32_t*)alloc((size_t)N * 4);
    uint32_t* bsum  = (uint32_t*)alloc(1024 * 4);
    uint32_t* boff  = (uint32_t*)alloc(1024 * 4);
    uint32_t* bsum2 = (uint32_t*)alloc(512);
    uint32_t* slot  = (uint32_t*)alloc((size_t)E * 4);
    float*    dinv  = (float*)alloc((size_t)N * 4);
    float*    A     = (float*)alloc((size_t)N * 128 * 4);   // layer-1 activations

    const int zspan = (int)(((char*)cur - (char*)cnt) / 4) + N;  // cnt..cur inclusive
    const int nblk_edges = (E + 255) / 256;       // 2500
    const int nblk_scan  = (N + 1023) / 1024;     // 98

    // --- graph structure ---
    zero_u32<<<(zspan + 255) / 256, 256, 0, stream>>>(cnt, zspan);
    count_dst<<<nblk_edges, 256, 0, stream>>>(dst, cnt, E);
    scan_blocks<<<nblk_scan, 256, 0, stream>>>(cnt, offs, bsum, N);
    scan_blocks<<<1, 256, 0, stream>>>(bsum, boff, bsum2, nblk_scan);
    add_boff_dinv<<<nblk_scan, 256, 0, stream>>>(offs, boff, cnt, dinv, N);
    fill_csr<<<nblk_edges, 256, 0, stream>>>(src, dst, offs, cur, slot, E);

    // --- layer 1: A = relu( (A_hat x) W1 + b1 ) ---
    fused_layer1<<<N / 32, 256, 0, stream>>>(x, offs, cnt, slot, dinv, W1, b1, A);

    // --- layer 2: out = (A_hat A) W2 + b2 ---
    fused_layer2<<<N / 32, 256, 0, stream>>>(A, offs, cnt, slot, dinv, W2, b2, out);
}

// Round 5
// 315.102 us; speedup vs baseline: 17.8431x; 17.8431x over previous
//
#include <hip/hip_runtime.h>
#include <stdint.h>

#define N_NODES 100000

// ---------------------------------------------------------------- CSR build
__global__ void zero_u32(uint32_t* p, int n){
    int i = blockIdx.x * 256 + threadIdx.x;
    if (i < n) p[i] = 0u;
}

__global__ void count_dst(const int* __restrict__ dst, uint32_t* __restrict__ cnt, int E){
    int e = blockIdx.x * 256 + threadIdx.x;
    if (e < E) atomicAdd((unsigned int*)&cnt[dst[e]], 1u);
}

// block-level scan over 1024 elements (Hillis-Steele in LDS).
__global__ void scan_blocks(const uint32_t* __restrict__ in, uint32_t* __restrict__ out,
                            uint32_t* __restrict__ bsum, int n){
    __shared__ uint32_t tmp[1024];
    int base = blockIdx.x * 1024;
    for (int j = threadIdx.x; j < 1024; j += 256)
        tmp[j] = (base + j < n) ? in[base + j] : 0u;
    __syncthreads();
    for (int off = 1; off < 1024; off <<= 1){
        uint32_t v[4];
        for (int j = 0; j < 4; j++){
            int i = threadIdx.x + j * 256;
            v[j] = (i >= off) ? tmp[i - off] : 0u;
        }
        __syncthreads();
        for (int j = 0; j < 4; j++){
            int i = threadIdx.x + j * 256;
            tmp[i] += v[j];
        }
        __syncthreads();
    }
    for (int j = threadIdx.x; j < 1024; j += 256)
        if (base + j < n) out[base + j] = (j > 0) ? tmp[j - 1] : 0u;
    if (threadIdx.x == 0) bsum[blockIdx.x] = tmp[1023];
}

// add block offsets to the scan AND compute dinv (fused: both read per-node arrays)
__global__ void add_boff_dinv(uint32_t* __restrict__ out, const uint32_t* __restrict__ boff,
                              const uint32_t* __restrict__ cnt, float* __restrict__ dinv, int n){
    int base = blockIdx.x * 1024;
    uint32_t add = boff[blockIdx.x];
    for (int j = threadIdx.x; j < 1024; j += 256){
        int i = base + j;
        if (i < n){
            out[i] += add;
            dinv[i] = rsqrtf((float)(cnt[i] + 1u));   // +1 self-loop; always > 0
        }
    }
}

__global__ void fill_csr(const int* __restrict__ src, const int* __restrict__ dst,
                         const uint32_t* __restrict__ off, uint32_t* __restrict__ cur,
                         uint32_t* __restrict__ slot, int E){
    int e = blockIdx.x * 256 + threadIdx.x;
    if (e < E){
        int d = dst[e];
        uint32_t p = atomicAdd((unsigned int*)&cur[d], 1u);
        slot[off[d] + p] = (uint32_t)src[e];
    }
}

// ---------------------------------------------------------------- aggregation (device helper)
// Pull-CSR aggregate of 8 nodes per wave into swizzled LDS tile xT.
// xT word(k,r) = k*32 + 4*((r>>2)^((k>>2)&7)) + (r&3): writes spread over 8 banks,
// float4 reads stay contiguous/aligned. 2x unrolled edge loop = 2 independent
// load chains (MLP) without the register pressure that spilled in round 4.
__device__ __forceinline__ void aggregate_tile(const float* __restrict__ X,
        const uint32_t* __restrict__ offs, const uint32_t* __restrict__ cnt,
        const uint32_t* __restrict__ slot, const float* __restrict__ dinv,
        float* __restrict__ xT, int r0, int tid){
    int wid = tid >> 6, lane = tid & 63;
    const float2* X2 = (const float2*)X;
    #pragma unroll 1
    for (int i = 0; i < 8; i++){
        int r = wid * 8 + i;
        int g = r0 + r;
        uint32_t o = offs[g], c = cnt[g];
        float accx = 0.f, accy = 0.f;
        uint32_t e = 0;
        #pragma unroll 1
        for (; e + 2 <= c; e += 2){
            uint32_t s0 = slot[o + e + 0], s1 = slot[o + e + 1];
            float d0 = dinv[s0], d1 = dinv[s1];
            float2 v0 = X2[(size_t)s0 * 64 + lane];
            float2 v1 = X2[(size_t)s1 * 64 + lane];
            accx += d0 * v0.x + d1 * v1.x;
            accy += d0 * v0.y + d1 * v1.y;
        }
        if (e < c){
            uint32_t s = slot[o + e];
            float ds = dinv[s];
            float2 v = X2[(size_t)s * 64 + lane];
            accx += ds * v.x;
            accy += ds * v.y;
        }
        float dd = dinv[g];
        float2 self = X2[(size_t)g * 64 + lane];
        float ax = dd * (accx + dd * self.x);
        float ay = dd * (accy + dd * self.y);
        int sw = (((r >> 2) ^ ((lane >> 1) & 7)) << 2) + (r & 3);   // mask = (k>>2)&7 for k=2*lane{,+1}
        xT[(2 * lane + 0) * 32 + sw] = ax;
        xT[(2 * lane + 1) * 32 + sw] = ay;
    }
}

// ---------------------------------------------------------------- fused layer 1
// out = relu( (A_hat x) @ W1 + b1 ), 32 nodes/block, 256 threads, LDS = 32 KiB.
__global__ __launch_bounds__(256) void fused_layer1(const float* __restrict__ X,
        const uint32_t* __restrict__ offs, const uint32_t* __restrict__ cnt,
        const uint32_t* __restrict__ slot, const float* __restrict__ dinv,
        const float* __restrict__ W, const float* __restrict__ bias,
        float* __restrict__ OUT){
    __shared__ float Wl[32 * 128];    // 16 KiB (one 32-row K-chunk of W)
    __shared__ float xT[128 * 32];    // 16 KiB, swizzled [k][r]
    int tid = threadIdx.x;
    int r0 = blockIdx.x * 32;

    aggregate_tile(X, offs, cnt, slot, dinv, xT, r0, tid);

    const float4* W4 = (const float4*)W;    // [128][128] row-major -> 32 float4/row
    float4* Wl4 = (float4*)Wl;
    const float4* xT4 = (const float4*)xT;
    int cg = tid & 31, rg = tid >> 5;
    float4 acc0 = {0,0,0,0}, acc1 = {0,0,0,0}, acc2 = {0,0,0,0}, acc3 = {0,0,0,0};

    #pragma unroll 1
    for (int chunk = 0; chunk < 4; chunk++){
        __syncthreads();                    // xT ready (1st) / prev chunk consumed (rest)
        for (int j = tid; j < 1024; j += 256) Wl4[j] = W4[chunk * 1024 + j];
        __syncthreads();
        #pragma unroll 8
        for (int kk = 0; kk < 32; kk++){
            int k = chunk * 32 + kk;
            float4 w  = Wl4[kk * 32 + cg];
            float4 xv = xT4[k * 8 + (rg ^ ((k >> 2) & 7))];
            acc0.x += xv.x * w.x; acc0.y += xv.x * w.y; acc0.z += xv.x * w.z; acc0.w += xv.x * w.w;
            acc1.x += xv.y * w.x; acc1.y += xv.y * w.y; acc1.z += xv.y * w.z; acc1.w += xv.y * w.w;
            acc2.x += xv.z * w.x; acc2.y += xv.z * w.y; acc2.z += xv.z * w.z; acc2.w += xv.z * w.w;
            acc3.x += xv.w * w.x; acc3.y += xv.w * w.y; acc3.z += xv.w * w.z; acc3.w += xv.w * w.w;
        }
    }

    float4 b = ((const float4*)bias)[cg];
    float4* O4 = (float4*)OUT;
    int rowbase = r0 + rg * 4;
    float4 o0 = {fmaxf(acc0.x + b.x, 0.f), fmaxf(acc0.y + b.y, 0.f), fmaxf(acc0.z + b.z, 0.f), fmaxf(acc0.w + b.w, 0.f)};
    float4 o1 = {fmaxf(acc1.x + b.x, 0.f), fmaxf(acc1.y + b.y, 0.f), fmaxf(acc1.z + b.z, 0.f), fmaxf(acc1.w + b.w, 0.f)};
    float4 o2 = {fmaxf(acc2.x + b.x, 0.f), fmaxf(acc2.y + b.y, 0.f), fmaxf(acc2.z + b.z, 0.f), fmaxf(acc2.w + b.w, 0.f)};
    float4 o3 = {fmaxf(acc3.x + b.x, 0.f), fmaxf(acc3.y + b.y, 0.f), fmaxf(acc3.z + b.z, 0.f), fmaxf(acc3.w + b.w, 0.f)};
    O4[(size_t)(rowbase + 0) * 32 + cg] = o0;
    O4[(size_t)(rowbase + 1) * 32 + cg] = o1;
    O4[(size_t)(rowbase + 2) * 32 + cg] = o2;
    O4[(size_t)(rowbase + 3) * 32 + cg] = o3;
}

// ---------------------------------------------------------------- fused layer 2
// out = (A_hat h1) @ W2 + b2, 32 nodes/block, 256 threads, LDS = 26 KiB.
__global__ __launch_bounds__(256) void fused_layer2(const float* __restrict__ H,
        const uint32_t* __restrict__ offs, const uint32_t* __restrict__ cnt,
        const uint32_t* __restrict__ slot, const float* __restrict__ dinv,
        const float* __restrict__ W, const float* __restrict__ bias,
        float* __restrict__ OUT){
    __shared__ float Wl[64 * 40];     // 10 KiB (one 64-row K-chunk of W2)
    __shared__ float xT[128 * 32];    // 16 KiB, swizzled [k][r]
    int tid = threadIdx.x;
    int r0 = blockIdx.x * 32;

    aggregate_tile(H, offs, cnt, slot, dinv, xT, r0, tid);

    const float4* W4 = (const float4*)W;   // [128][40] -> 10 float4/row
    float4* Wl4 = (float4*)Wl;
    int r = tid >> 3, cw = tid & 7;        // 32 rows x 8 col-groups (5 cols each)
    int rhi = r >> 2, rlo = r & 3;
    float acc[5] = {0.f, 0.f, 0.f, 0.f, 0.f};

    #pragma unroll 1
    for (int chunk = 0; chunk < 2; chunk++){
        __syncthreads();
        for (int j = tid; j < 640; j += 256) Wl4[j] = W4[chunk * 640 + j];
        __syncthreads();
        #pragma unroll 8
        for (int kk = 0; kk < 64; kk++){
            int k = chunk * 64 + kk;
            float xv = xT[k * 32 + (((rhi ^ ((k >> 2) & 7)) << 2) + rlo)];
            #pragma unroll
            for (int j = 0; j < 5; j++)
                acc[j] += xv * Wl[kk * 40 + 5 * cw + j];
        }
    }
    int g = r0 + r;
    #pragma unroll
    for (int j = 0; j < 5; j++)
        OUT[(size_t)g * 40 + 5 * cw + j] = acc[j] + bias[5 * cw + j];
}

// ---------------------------------------------------------------- launch
extern "C" void kernel_launch(void* const* d_in, const int* in_sizes, int n_in,
                              void* d_out, int out_size, void* d_ws, size_t ws_size,
                              hipStream_t stream) {
    const float* x   = (const float*)d_in[0];
    const int*   ei  = (const int*)d_in[1];      // int32 (harness converts integer inputs)
    const float* W1  = (const float*)d_in[2];
    const float* b1  = (const float*)d_in[3];
    const float* W2  = (const float*)d_in[4];
    const float* b2  = (const float*)d_in[5];
    float*       out = (float*)d_out;

    const int N = N_NODES;
    const int E = in_sizes[1] / 2;
    const int* src = ei;
    const int* dst = ei + E;

    // workspace carve-up (512B-aligned). cnt/offs/cur are contiguous -> one zeroing pass.
    char* ws = (char*)d_ws;
    size_t o = 0;
    auto alloc = [&](size_t bytes) -> char* {
        char* p = ws + o;
        o += (bytes + 511) & ~(size_t)511;
        return p;
    };
    uint32_t* cnt   = (uint32_t*)alloc((size_t)N * 4);
    uint32_t* offs  = (uint32_t*)alloc((size_t)N * 4);
    uint32_t* cur   = (uint32_t*)alloc((size_t)N * 4);
    uint32_t* bsum  = (uint32_t*)alloc(1024 * 4);
    uint32_t* boff  = (uint32_t*)alloc(1024 * 4);
    uint32_t* bsum2 = (uint32_t*)alloc(512);
    uint32_t* slot  = (uint32_t*)alloc((size_t)E * 4);
    float*    dinv  = (float*)alloc((size_t)N * 4);
    float*    A     = (float*)alloc((size_t)N * 128 * 4);   // layer-1 activations

    const int zspan = (int)(((char*)cur - (char*)cnt) / 4) + N;  // cnt..cur inclusive
    const int nblk_edges = (E + 255) / 256;       // 2500
    const int nblk_scan  = (N + 1023) / 1024;     // 98

    // --- graph structure ---
    zero_u32<<<(zspan + 255) / 256, 256, 0, stream>>>(cnt, zspan);
    count_dst<<<nblk_edges, 256, 0, stream>>>(dst, cnt, E);
    scan_blocks<<<nblk_scan, 256, 0, stream>>>(cnt, offs, bsum, N);
    scan_blocks<<<1, 256, 0, stream>>>(bsum, boff, bsum2, nblk_scan);
    add_boff_dinv<<<nblk_scan, 256, 0, stream>>>(offs, boff, cnt, dinv, N);
    fill_csr<<<nblk_edges, 256, 0, stream>>>(src, dst, offs, cur, slot, E);

    // --- layer 1: A = relu( (A_hat x) W1 + b1 ) ---
    fused_layer1<<<N / 32, 256, 0, stream>>>(x, offs, cnt, slot, dinv, W1, b1, A);

    // --- layer 2: out = (A_hat A) W2 + b2 ---
    fused_layer2<<<N / 32, 256, 0, stream>>>(A, offs, cnt, slot, dinv, W2, b2, out);
}

// Round 6
// 270.530 us; speedup vs baseline: 20.7829x; 1.1648x over previous
//
#include <hip/hip_runtime.h>
#include <stdint.h>

#define N_NODES 100000

// ---------------------------------------------------------------- CSR build
__global__ void zero_u32(uint32_t* p, int n){
    int i = blockIdx.x * 256 + threadIdx.x;
    if (i < n) p[i] = 0u;
}

__global__ void count_dst(const int* __restrict__ dst, uint32_t* __restrict__ cnt, int E){
    int e = blockIdx.x * 256 + threadIdx.x;
    if (e < E) atomicAdd((unsigned int*)&cnt[dst[e]], 1u);
}

// block-level scan over 1024 elements (Hillis-Steele in LDS).
__global__ void scan_blocks(const uint32_t* __restrict__ in, uint32_t* __restrict__ out,
                            uint32_t* __restrict__ bsum, int n){
    __shared__ uint32_t tmp[1024];
    int base = blockIdx.x * 1024;
    for (int j = threadIdx.x; j < 1024; j += 256)
        tmp[j] = (base + j < n) ? in[base + j] : 0u;
    __syncthreads();
    for (int off = 1; off < 1024; off <<= 1){
        uint32_t v[4];
        for (int j = 0; j < 4; j++){
            int i = threadIdx.x + j * 256;
            v[j] = (i >= off) ? tmp[i - off] : 0u;
        }
        __syncthreads();
        for (int j = 0; j < 4; j++){
            int i = threadIdx.x + j * 256;
            tmp[i] += v[j];
        }
        __syncthreads();
    }
    for (int j = threadIdx.x; j < 1024; j += 256)
        if (base + j < n) out[base + j] = (j > 0) ? tmp[j - 1] : 0u;
    if (threadIdx.x == 0) bsum[blockIdx.x] = tmp[1023];
}

// add block offsets to the scan AND compute dinv (fused: both read per-node arrays)
__global__ void add_boff_dinv(uint32_t* __restrict__ out, const uint32_t* __restrict__ boff,
                              const uint32_t* __restrict__ cnt, float* __restrict__ dinv, int n){
    int base = blockIdx.x * 1024;
    uint32_t add = boff[blockIdx.x];
    for (int j = threadIdx.x; j < 1024; j += 256){
        int i = base + j;
        if (i < n){
            out[i] += add;
            dinv[i] = rsqrtf((float)(cnt[i] + 1u));   // +1 self-loop; always > 0
        }
    }
}

__global__ void fill_csr(const int* __restrict__ src, const int* __restrict__ dst,
                         const uint32_t* __restrict__ off, uint32_t* __restrict__ cur,
                         uint32_t* __restrict__ slot, int E){
    int e = blockIdx.x * 256 + threadIdx.x;
    if (e < E){
        int d = dst[e];
        uint32_t p = atomicAdd((unsigned int*)&cur[d], 1u);
        slot[off[d] + p] = (uint32_t)src[e];
    }
}

// ---------------------------------------------------------------- aggregation (device helper)
// Pull-CSR aggregate of 8 nodes per wave into swizzled LDS tile xT.
// NEW: 32 lanes per node (float4 each = full 128-feature row per instruction),
// 2 nodes in parallel per wave (lane halves), 4 serial node-iters, 2x edge
// unroll -> 4 independent gather chains per wave.
// xT word(k,r) = k*32 + 4*((r>>2)^((k>>2)&7)) + (r&3); here k>>2 == l, so
// sw = 4*((r>>2)^(l&7)) + (r&3). GEMM float4 reads stay conflict-free.
__device__ __forceinline__ void aggregate_tile(const float* __restrict__ X,
        const uint32_t* __restrict__ offs, const uint32_t* __restrict__ cnt,
        const uint32_t* __restrict__ slot, const float* __restrict__ dinv,
        float* __restrict__ xT, int r0, int tid){
    int wid = tid >> 6, lane = tid & 63;
    int h = lane >> 5, l = lane & 31;
    const float4* X4 = (const float4*)X;
    #pragma unroll 1
    for (int i = 0; i < 4; i++){
        int r = wid * 8 + 2 * i + h;
        int g = r0 + r;
        uint32_t o = offs[g], c = cnt[g];
        float ax = 0.f, ay = 0.f, az = 0.f, aw = 0.f;
        uint32_t e = 0;
        #pragma unroll 1
        for (; e + 2 <= c; e += 2){
            uint32_t s0 = slot[o + e + 0], s1 = slot[o + e + 1];
            float d0 = dinv[s0], d1 = dinv[s1];
            float4 v0 = X4[(size_t)s0 * 32 + l];
            float4 v1 = X4[(size_t)s1 * 32 + l];
            ax += d0 * v0.x + d1 * v1.x;
            ay += d0 * v0.y + d1 * v1.y;
            az += d0 * v0.z + d1 * v1.z;
            aw += d0 * v0.w + d1 * v1.w;
        }
        if (e < c){
            uint32_t s = slot[o + e];
            float ds = dinv[s];
            float4 v = X4[(size_t)s * 32 + l];
            ax += ds * v.x; ay += ds * v.y; az += ds * v.z; aw += ds * v.w;
        }
        float dd = dinv[g];
        float4 self = X4[(size_t)g * 32 + l];
        int sw = (((r >> 2) ^ (l & 7)) << 2) + (r & 3);
        xT[(4 * l + 0) * 32 + sw] = dd * (ax + dd * self.x);
        xT[(4 * l + 1) * 32 + sw] = dd * (ay + dd * self.y);
        xT[(4 * l + 2) * 32 + sw] = dd * (az + dd * self.z);
        xT[(4 * l + 3) * 32 + sw] = dd * (aw + dd * self.w);
    }
}

// ---------------------------------------------------------------- fused layer 1
// out = relu( (A_hat x) @ W1 + b1 ), 32 nodes/block, 256 threads, LDS = 32 KiB.
__global__ __launch_bounds__(256) void fused_layer1(const float* __restrict__ X,
        const uint32_t* __restrict__ offs, const uint32_t* __restrict__ cnt,
        const uint32_t* __restrict__ slot, const float* __restrict__ dinv,
        const float* __restrict__ W, const float* __restrict__ bias,
        float* __restrict__ OUT){
    __shared__ float Wl[32 * 128];    // 16 KiB (one 32-row K-chunk of W)
    __shared__ float xT[128 * 32];    // 16 KiB, swizzled [k][r]
    int tid = threadIdx.x;
    int r0 = blockIdx.x * 32;

    aggregate_tile(X, offs, cnt, slot, dinv, xT, r0, tid);

    const float4* W4 = (const float4*)W;    // [128][128] row-major -> 32 float4/row
    float4* Wl4 = (float4*)Wl;
    const float4* xT4 = (const float4*)xT;
    int cg = tid & 31, rg = tid >> 5;
    float4 acc0 = {0,0,0,0}, acc1 = {0,0,0,0}, acc2 = {0,0,0,0}, acc3 = {0,0,0,0};

    #pragma unroll 1
    for (int chunk = 0; chunk < 4; chunk++){
        __syncthreads();                    // xT ready (1st) / prev chunk consumed (rest)
        for (int j = tid; j < 1024; j += 256) Wl4[j] = W4[chunk * 1024 + j];
        __syncthreads();
        #pragma unroll 8
        for (int kk = 0; kk < 32; kk++){
            int k = chunk * 32 + kk;
            float4 w  = Wl4[kk * 32 + cg];
            float4 xv = xT4[k * 8 + (rg ^ ((k >> 2) & 7))];
            acc0.x += xv.x * w.x; acc0.y += xv.x * w.y; acc0.z += xv.x * w.z; acc0.w += xv.x * w.w;
            acc1.x += xv.y * w.x; acc1.y += xv.y * w.y; acc1.z += xv.y * w.z; acc1.w += xv.y * w.w;
            acc2.x += xv.z * w.x; acc2.y += xv.z * w.y; acc2.z += xv.z * w.z; acc2.w += xv.z * w.w;
            acc3.x += xv.w * w.x; acc3.y += xv.w * w.y; acc3.z += xv.w * w.z; acc3.w += xv.w * w.w;
        }
    }

    float4 b = ((const float4*)bias)[cg];
    float4* O4 = (float4*)OUT;
    int rowbase = r0 + rg * 4;
    float4 o0 = {fmaxf(acc0.x + b.x, 0.f), fmaxf(acc0.y + b.y, 0.f), fmaxf(acc0.z + b.z, 0.f), fmaxf(acc0.w + b.w, 0.f)};
    float4 o1 = {fmaxf(acc1.x + b.x, 0.f), fmaxf(acc1.y + b.y, 0.f), fmaxf(acc1.z + b.z, 0.f), fmaxf(acc1.w + b.w, 0.f)};
    float4 o2 = {fmaxf(acc2.x + b.x, 0.f), fmaxf(acc2.y + b.y, 0.f), fmaxf(acc2.z + b.z, 0.f), fmaxf(acc2.w + b.w, 0.f)};
    float4 o3 = {fmaxf(acc3.x + b.x, 0.f), fmaxf(acc3.y + b.y, 0.f), fmaxf(acc3.z + b.z, 0.f), fmaxf(acc3.w + b.w, 0.f)};
    O4[(size_t)(rowbase + 0) * 32 + cg] = o0;
    O4[(size_t)(rowbase + 1) * 32 + cg] = o1;
    O4[(size_t)(rowbase + 2) * 32 + cg] = o2;
    O4[(size_t)(rowbase + 3) * 32 + cg] = o3;
}

// ---------------------------------------------------------------- fused layer 2
// out = (A_hat h1) @ W2 + b2, 32 nodes/block, 256 threads, LDS = 26 KiB.
__global__ __launch_bounds__(256) void fused_layer2(const float* __restrict__ H,
        const uint32_t* __restrict__ offs, const uint32_t* __restrict__ cnt,
        const uint32_t* __restrict__ slot, const float* __restrict__ dinv,
        const float* __restrict__ W, const float* __restrict__ bias,
        float* __restrict__ OUT){
    __shared__ float Wl[64 * 40];     // 10 KiB (one 64-row K-chunk of W2)
    __shared__ float xT[128 * 32];    // 16 KiB, swizzled [k][r]
    int tid = threadIdx.x;
    int r0 = blockIdx.x * 32;

    aggregate_tile(H, offs, cnt, slot, dinv, xT, r0, tid);

    const float4* W4 = (const float4*)W;   // [128][40] -> 10 float4/row
    float4* Wl4 = (float4*)Wl;
    int r = tid >> 3, cw = tid & 7;        // 32 rows x 8 col-groups (5 cols each)
    int rhi = r >> 2, rlo = r & 3;
    float acc[5] = {0.f, 0.f, 0.f, 0.f, 0.f};

    #pragma unroll 1
    for (int chunk = 0; chunk < 2; chunk++){
        __syncthreads();
        for (int j = tid; j < 640; j += 256) Wl4[j] = W4[chunk * 640 + j];
        __syncthreads();
        #pragma unroll 8
        for (int kk = 0; kk < 64; kk++){
            int k = chunk * 64 + kk;
            float xv = xT[k * 32 + (((rhi ^ ((k >> 2) & 7)) << 2) + rlo)];
            #pragma unroll
            for (int j = 0; j < 5; j++)
                acc[j] += xv * Wl[kk * 40 + 5 * cw + j];
        }
    }
    int g = r0 + r;
    #pragma unroll
    for (int j = 0; j < 5; j++)
        OUT[(size_t)g * 40 + 5 * cw + j] = acc[j] + bias[5 * cw + j];
}

// ---------------------------------------------------------------- launch
extern "C" void kernel_launch(void* const* d_in, const int* in_sizes, int n_in,
                              void* d_out, int out_size, void* d_ws, size_t ws_size,
                              hipStream_t stream) {
    const float* x   = (const float*)d_in[0];
    const int*   ei  = (const int*)d_in[1];      // int32 (harness converts integer inputs)
    const float* W1  = (const float*)d_in[2];
    const float* b1  = (const float*)d_in[3];
    const float* W2  = (const float*)d_in[4];
    const float* b2  = (const float*)d_in[5];
    float*       out = (float*)d_out;

    const int N = N_NODES;
    const int E = in_sizes[1] / 2;
    const int* src = ei;
    const int* dst = ei + E;

    // workspace carve-up (512B-aligned). cnt/offs/cur are contiguous -> one zeroing pass.
    char* ws = (char*)d_ws;
    size_t o = 0;
    auto alloc = [&](size_t bytes) -> char* {
        char* p = ws + o;
        o += (bytes + 511) & ~(size_t)511;
        return p;
    };
    uint32_t* cnt   = (uint32_t*)alloc((size_t)N * 4);
    uint32_t* offs  = (uint32_t*)alloc((size_t)N * 4);
    uint32_t* cur   = (uint32_t*)alloc((size_t)N * 4);
    uint32_t* bsum  = (uint32_t*)alloc(1024 * 4);
    uint32_t* boff  = (uint32_t*)alloc(1024 * 4);
    uint32_t* bsum2 = (uint32_t*)alloc(512);
    uint32_t* slot  = (uint32_t*)alloc((size_t)E * 4);
    float*    dinv  = (float*)alloc((size_t)N * 4);
    float*    A     = (float*)alloc((size_t)N * 128 * 4);   // layer-1 activations

    const int zspan = (int)(((char*)cur - (char*)cnt) / 4) + N;  // cnt..cur inclusive
    const int nblk_edges = (E + 255) / 256;       // 2500
    const int nblk_scan  = (N + 1023) / 1024;     // 98

    // --- graph structure ---
    zero_u32<<<(zspan + 255) / 256, 256, 0, stream>>>(cnt, zspan);
    count_dst<<<nblk_edges, 256, 0, stream>>>(dst, cnt, E);
    scan_blocks<<<nblk_scan, 256, 0, stream>>>(cnt, offs, bsum, N);
    scan_blocks<<<1, 256, 0, stream>>>(bsum, boff, bsum2, nblk_scan);
    add_boff_dinv<<<nblk_scan, 256, 0, stream>>>(offs, boff, cnt, dinv, N);
    fill_csr<<<nblk_edges, 256, 0, stream>>>(src, dst, offs, cur, slot, E);

    // --- layer 1: A = relu( (A_hat x) W1 + b1 ) ---
    fused_layer1<<<N / 32, 256, 0, stream>>>(x, offs, cnt, slot, dinv, W1, b1, A);

    // --- layer 2: out = (A_hat A) W2 + b2 ---
    fused_layer2<<<N / 32, 256, 0, stream>>>(A, offs, cnt, slot, dinv, W2, b2, out);
}

// Round 7
// 262.344 us; speedup vs baseline: 21.4314x; 1.0312x over previous
//
#include <hip/hip_runtime.h>
#include <stdint.h>

#define N_NODES 100000

// ---------------------------------------------------------------- CSR build
__global__ void zero_u32(uint32_t* p, int n){
    int i = blockIdx.x * 256 + threadIdx.x;
    if (i < n) p[i] = 0u;
}

__global__ void count_dst(const int* __restrict__ dst, uint32_t* __restrict__ cnt, int E){
    int e = blockIdx.x * 256 + threadIdx.x;
    if (e < E) atomicAdd((unsigned int*)&cnt[dst[e]], 1u);
}

// block-level scan over 1024 elements (Hillis-Steele in LDS).
__global__ void scan_blocks(const uint32_t* __restrict__ in, uint32_t* __restrict__ out,
                            uint32_t* __restrict__ bsum, int n){
    __shared__ uint32_t tmp[1024];
    int base = blockIdx.x * 1024;
    for (int j = threadIdx.x; j < 1024; j += 256)
        tmp[j] = (base + j < n) ? in[base + j] : 0u;
    __syncthreads();
    for (int off = 1; off < 1024; off <<= 1){
        uint32_t v[4];
        for (int j = 0; j < 4; j++){
            int i = threadIdx.x + j * 256;
            v[j] = (i >= off) ? tmp[i - off] : 0u;
        }
        __syncthreads();
        for (int j = 0; j < 4; j++){
            int i = threadIdx.x + j * 256;
            tmp[i] += v[j];
        }
        __syncthreads();
    }
    for (int j = threadIdx.x; j < 1024; j += 256)
        if (base + j < n) out[base + j] = (j > 0) ? tmp[j - 1] : 0u;
    if (threadIdx.x == 0) bsum[blockIdx.x] = tmp[1023];
}

// add block offsets to the scan AND compute dinv (fused: both read per-node arrays)
__global__ void add_boff_dinv(uint32_t* __restrict__ out, const uint32_t* __restrict__ boff,
                              const uint32_t* __restrict__ cnt, float* __restrict__ dinv, int n){
    int base = blockIdx.x * 1024;
    uint32_t add = boff[blockIdx.x];
    for (int j = threadIdx.x; j < 1024; j += 256){
        int i = base + j;
        if (i < n){
            out[i] += add;
            dinv[i] = rsqrtf((float)(cnt[i] + 1u));   // +1 self-loop; always > 0
        }
    }
}

__global__ void fill_csr(const int* __restrict__ src, const int* __restrict__ dst,
                         const uint32_t* __restrict__ off, uint32_t* __restrict__ cur,
                         uint32_t* __restrict__ slot, int E){
    int e = blockIdx.x * 256 + threadIdx.x;
    if (e < E){
        int d = dst[e];
        uint32_t p = atomicAdd((unsigned int*)&cur[d], 1u);
        slot[off[d] + p] = (uint32_t)src[e];
    }
}

// ---------------------------------------------------------------- aggregation (device helper)
// Pull-CSR aggregate of 8 nodes per wave into swizzled LDS tile xT.
// 32 lanes per node (float4 each = full 128-feature row), 2 nodes per wave.
// Index-cache scheme: lane l loads slot[o+l] and its dinv in ONE coalesced
// round-trip; the gather loop gets (s,d) per edge via __shfl (register-only),
// so all row gathers are address-independent and pipeline freely. Gathers run
// in padded groups of 8: lanes past rem hold idx=0,d=0 -> read row 0 (L1-hot,
// in-bounds) and add 0. No divergent remainder loop.
// xT word(k,r) = k*32 + 4*((r>>2)^((k>>2)&7)) + (r&3); here k>>2 == l, so
// sw = 4*((r>>2)^(l&7)) + (r&3). GEMM float4 reads stay conflict-free.
__device__ __forceinline__ void aggregate_tile(const float* __restrict__ X,
        const uint32_t* __restrict__ offs, const uint32_t* __restrict__ cnt,
        const uint32_t* __restrict__ slot, const float* __restrict__ dinv,
        float* __restrict__ xT, int r0, int tid){
    int wid = tid >> 6, lane = tid & 63;
    int h = lane >> 5, l = lane & 31;
    const float4* X4 = (const float4*)X;
    #pragma unroll 1
    for (int i = 0; i < 4; i++){
        int r = wid * 8 + 2 * i + h;
        int g = r0 + r;
        uint32_t o = offs[g], c = cnt[g];
        float ax = 0.f, ay = 0.f, az = 0.f, aw = 0.f;
        #pragma unroll 1
        for (uint32_t base = 0; base < c; base += 32){
            int rem = (int)(c - base); if (rem > 32) rem = 32;
            uint32_t idx = 0u; float ds = 0.f;
            if (l < rem){
                idx = slot[o + base + (uint32_t)l];
                ds = dinv[idx];
            }
            int groups = (rem + 7) >> 3;
            #pragma unroll 1
            for (int gq = 0; gq < groups; gq++){
                int eb = gq * 8;
                #pragma unroll
                for (int j = 0; j < 8; j++){
                    uint32_t s = (uint32_t)__shfl((int)idx, eb + j, 32);
                    float d = __shfl(ds, eb + j, 32);
                    float4 v = X4[(size_t)s * 32 + l];
                    ax += d * v.x; ay += d * v.y; az += d * v.z; aw += d * v.w;
                }
            }
        }
        float dd = dinv[g];
        float4 self = X4[(size_t)g * 32 + l];
        int sw = (((r >> 2) ^ (l & 7)) << 2) + (r & 3);
        xT[(4 * l + 0) * 32 + sw] = dd * (ax + dd * self.x);
        xT[(4 * l + 1) * 32 + sw] = dd * (ay + dd * self.y);
        xT[(4 * l + 2) * 32 + sw] = dd * (az + dd * self.z);
        xT[(4 * l + 3) * 32 + sw] = dd * (aw + dd * self.w);
    }
}

// ---------------------------------------------------------------- fused layer 1
// out = relu( (A_hat x) @ W1 + b1 ), 32 nodes/block, 256 threads, LDS = 32 KiB.
__global__ __launch_bounds__(256) void fused_layer1(const float* __restrict__ X,
        const uint32_t* __restrict__ offs, const uint32_t* __restrict__ cnt,
        const uint32_t* __restrict__ slot, const float* __restrict__ dinv,
        const float* __restrict__ W, const float* __restrict__ bias,
        float* __restrict__ OUT){
    __shared__ float Wl[32 * 128];    // 16 KiB (one 32-row K-chunk of W)
    __shared__ float xT[128 * 32];    // 16 KiB, swizzled [k][r]
    int tid = threadIdx.x;
    int r0 = blockIdx.x * 32;

    aggregate_tile(X, offs, cnt, slot, dinv, xT, r0, tid);

    const float4* W4 = (const float4*)W;    // [128][128] row-major -> 32 float4/row
    float4* Wl4 = (float4*)Wl;
    const float4* xT4 = (const float4*)xT;
    int cg = tid & 31, rg = tid >> 5;
    float4 acc0 = {0,0,0,0}, acc1 = {0,0,0,0}, acc2 = {0,0,0,0}, acc3 = {0,0,0,0};

    #pragma unroll 1
    for (int chunk = 0; chunk < 4; chunk++){
        __syncthreads();                    // xT ready (1st) / prev chunk consumed (rest)
        for (int j = tid; j < 1024; j += 256) Wl4[j] = W4[chunk * 1024 + j];
        __syncthreads();
        #pragma unroll 8
        for (int kk = 0; kk < 32; kk++){
            int k = chunk * 32 + kk;
            float4 w  = Wl4[kk * 32 + cg];
            float4 xv = xT4[k * 8 + (rg ^ ((k >> 2) & 7))];
            acc0.x += xv.x * w.x; acc0.y += xv.x * w.y; acc0.z += xv.x * w.z; acc0.w += xv.x * w.w;
            acc1.x += xv.y * w.x; acc1.y += xv.y * w.y; acc1.z += xv.y * w.z; acc1.w += xv.y * w.w;
            acc2.x += xv.z * w.x; acc2.y += xv.z * w.y; acc2.z += xv.z * w.z; acc2.w += xv.z * w.w;
            acc3.x += xv.w * w.x; acc3.y += xv.w * w.y; acc3.z += xv.w * w.z; acc3.w += xv.w * w.w;
        }
    }

    float4 b = ((const float4*)bias)[cg];
    float4* O4 = (float4*)OUT;
    int rowbase = r0 + rg * 4;
    float4 o0 = {fmaxf(acc0.x + b.x, 0.f), fmaxf(acc0.y + b.y, 0.f), fmaxf(acc0.z + b.z, 0.f), fmaxf(acc0.w + b.w, 0.f)};
    float4 o1 = {fmaxf(acc1.x + b.x, 0.f), fmaxf(acc1.y + b.y, 0.f), fmaxf(acc1.z + b.z, 0.f), fmaxf(acc1.w + b.w, 0.f)};
    float4 o2 = {fmaxf(acc2.x + b.x, 0.f), fmaxf(acc2.y + b.y, 0.f), fmaxf(acc2.z + b.z, 0.f), fmaxf(acc2.w + b.w, 0.f)};
    float4 o3 = {fmaxf(acc3.x + b.x, 0.f), fmaxf(acc3.y + b.y, 0.f), fmaxf(acc3.z + b.z, 0.f), fmaxf(acc3.w + b.w, 0.f)};
    O4[(size_t)(rowbase + 0) * 32 + cg] = o0;
    O4[(size_t)(rowbase + 1) * 32 + cg] = o1;
    O4[(size_t)(rowbase + 2) * 32 + cg] = o2;
    O4[(size_t)(rowbase + 3) * 32 + cg] = o3;
}

// ---------------------------------------------------------------- fused layer 2
// out = (A_hat h1) @ W2 + b2, 32 nodes/block, 256 threads, LDS = 26 KiB.
__global__ __launch_bounds__(256) void fused_layer2(const float* __restrict__ H,
        const uint32_t* __restrict__ offs, const uint32_t* __restrict__ cnt,
        const uint32_t* __restrict__ slot, const float* __restrict__ dinv,
        const float* __restrict__ W, const float* __restrict__ bias,
        float* __restrict__ OUT){
    __shared__ float Wl[64 * 40];     // 10 KiB (one 64-row K-chunk of W2)
    __shared__ float xT[128 * 32];    // 16 KiB, swizzled [k][r]
    int tid = threadIdx.x;
    int r0 = blockIdx.x * 32;

    aggregate_tile(H, offs, cnt, slot, dinv, xT, r0, tid);

    const float4* W4 = (const float4*)W;   // [128][40] -> 10 float4/row
    float4* Wl4 = (float4*)Wl;
    int r = tid >> 3, cw = tid & 7;        // 32 rows x 8 col-groups (5 cols each)
    int rhi = r >> 2, rlo = r & 3;
    float acc[5] = {0.f, 0.f, 0.f, 0.f, 0.f};

    #pragma unroll 1
    for (int chunk = 0; chunk < 2; chunk++){
        __syncthreads();
        for (int j = tid; j < 640; j += 256) Wl4[j] = W4[chunk * 640 + j];
        __syncthreads();
        #pragma unroll 8
        for (int kk = 0; kk < 64; kk++){
            int k = chunk * 64 + kk;
            float xv = xT[k * 32 + (((rhi ^ ((k >> 2) & 7)) << 2) + rlo)];
            #pragma unroll
            for (int j = 0; j < 5; j++)
                acc[j] += xv * Wl[kk * 40 + 5 * cw + j];
        }
    }
    int g = r0 + r;
    #pragma unroll
    for (int j = 0; j < 5; j++)
        OUT[(size_t)g * 40 + 5 * cw + j] = acc[j] + bias[5 * cw + j];
}

// ---------------------------------------------------------------- launch
extern "C" void kernel_launch(void* const* d_in, const int* in_sizes, int n_in,
                              void* d_out, int out_size, void* d_ws, size_t ws_size,
                              hipStream_t stream) {
    const float* x   = (const float*)d_in[0];
    const int*   ei  = (const int*)d_in[1];      // int32 (harness converts integer inputs)
    const float* W1  = (const float*)d_in[2];
    const float* b1  = (const float*)d_in[3];
    const float* W2  = (const float*)d_in[4];
    const float* b2  = (const float*)d_in[5];
    float*       out = (float*)d_out;

    const int N = N_NODES;
    const int E = in_sizes[1] / 2;
    const int* src = ei;
    const int* dst = ei + E;

    // workspace carve-up (512B-aligned). cnt/offs/cur are contiguous -> one zeroing pass.
    char* ws = (char*)d_ws;
    size_t o = 0;
    auto alloc = [&](size_t bytes) -> char* {
        char* p = ws + o;
        o += (bytes + 511) & ~(size_t)511;
        return p;
    };
    uint32_t* cnt   = (uint32_t*)alloc((size_t)N * 4);
    uint32_t* offs  = (uint32_t*)alloc((size_t)N * 4);
    uint32_t* cur   = (uint32_t*)alloc((size_t)N * 4);
    uint32_t* bsum  = (uint32_t*)alloc(1024 * 4);
    uint32_t* boff  = (uint32_t*)alloc(1024 * 4);
    uint32_t* bsum2 = (uint32_t*)alloc(512);
    uint32_t* slot  = (uint32_t*)alloc((size_t)E * 4);
    float*    dinv  = (float*)alloc((size_t)N * 4);
    float*    A     = (float*)alloc((size_t)N * 128 * 4);   // layer-1 activations

    const int zspan = (int)(((char*)cur - (char*)cnt) / 4) + N;  // cnt..cur inclusive
    const int nblk_edges = (E + 255) / 256;       // 2500
    const int nblk_scan  = (N + 1023) / 1024;     // 98

    // --- graph structure ---
    zero_u32<<<(zspan + 255) / 256, 256, 0, stream>>>(cnt, zspan);
    count_dst<<<nblk_edges, 256, 0, stream>>>(dst, cnt, E);
    scan_blocks<<<nblk_scan, 256, 0, stream>>>(cnt, offs, bsum, N);
    scan_blocks<<<1, 256, 0, stream>>>(bsum, boff, bsum2, nblk_scan);
    add_boff_dinv<<<nblk_scan, 256, 0, stream>>>(offs, boff, cnt, dinv, N);
    fill_csr<<<nblk_edges, 256, 0, stream>>>(src, dst, offs, cur, slot, E);

    // --- layer 1: A = relu( (A_hat x) W1 + b1 ) ---
    fused_layer1<<<N / 32, 256, 0, stream>>>(x, offs, cnt, slot, dinv, W1, b1, A);

    // --- layer 2: out = (A_hat A) W2 + b2 ---
    fused_layer2<<<N / 32, 256, 0, stream>>>(A, offs, cnt, slot, dinv, W2, b2, out);
}

// Round 8
// 244.203 us; speedup vs baseline: 23.0234x; 1.0743x over previous
//
#include <hip/hip_runtime.h>
#include <stdint.h>

#define N_NODES 100000

// ---------------------------------------------------------------- bf16 helpers
__device__ __forceinline__ unsigned short f2bf(float f){
    uint32_t u = __float_as_uint(f);
    uint32_t r = (u + 0x7FFFu + ((u >> 16) & 1u)) >> 16;   // round-nearest-even
    return (unsigned short)r;
}
__device__ __forceinline__ float bf2f(unsigned short h){
    return __uint_as_float(((uint32_t)h) << 16);
}

// ---------------------------------------------------------------- CSR build
__global__ void zero_u32(uint32_t* p, int n){
    int i = blockIdx.x * 256 + threadIdx.x;
    if (i < n) p[i] = 0u;
}

__global__ void count_dst(const int* __restrict__ dst, uint32_t* __restrict__ cnt, int E){
    int e = blockIdx.x * 256 + threadIdx.x;
    if (e < E) atomicAdd((unsigned int*)&cnt[dst[e]], 1u);
}

// block-level scan over 1024 elements (Hillis-Steele in LDS).
__global__ void scan_blocks(const uint32_t* __restrict__ in, uint32_t* __restrict__ out,
                            uint32_t* __restrict__ bsum, int n){
    __shared__ uint32_t tmp[1024];
    int base = blockIdx.x * 1024;
    for (int j = threadIdx.x; j < 1024; j += 256)
        tmp[j] = (base + j < n) ? in[base + j] : 0u;
    __syncthreads();
    for (int off = 1; off < 1024; off <<= 1){
        uint32_t v[4];
        for (int j = 0; j < 4; j++){
            int i = threadIdx.x + j * 256;
            v[j] = (i >= off) ? tmp[i - off] : 0u;
        }
        __syncthreads();
        for (int j = 0; j < 4; j++){
            int i = threadIdx.x + j * 256;
            tmp[i] += v[j];
        }
        __syncthreads();
    }
    for (int j = threadIdx.x; j < 1024; j += 256)
        if (base + j < n) out[base + j] = (j > 0) ? tmp[j - 1] : 0u;
    if (threadIdx.x == 0) bsum[blockIdx.x] = tmp[1023];
}

// add block offsets to the scan AND compute dinv (fused: both read per-node arrays)
__global__ void add_boff_dinv(uint32_t* __restrict__ out, const uint32_t* __restrict__ boff,
                              const uint32_t* __restrict__ cnt, float* __restrict__ dinv, int n){
    int base = blockIdx.x * 1024;
    uint32_t add = boff[blockIdx.x];
    for (int j = threadIdx.x; j < 1024; j += 256){
        int i = base + j;
        if (i < n){
            out[i] += add;
            dinv[i] = rsqrtf((float)(cnt[i] + 1u));   // +1 self-loop; always > 0
        }
    }
}

__global__ void fill_csr(const int* __restrict__ src, const int* __restrict__ dst,
                         const uint32_t* __restrict__ off, uint32_t* __restrict__ cur,
                         uint32_t* __restrict__ slot, int E){
    int e = blockIdx.x * 256 + threadIdx.x;
    if (e < E){
        int d = dst[e];
        uint32_t p = atomicAdd((unsigned int*)&cur[d], 1u);
        slot[off[d] + p] = (uint32_t)src[e];
    }
}

// fp32 -> bf16 table conversion (4 elems/thread, coalesced)
__global__ void to_bf16(const float* __restrict__ in, unsigned short* __restrict__ outp, int n4){
    int i = blockIdx.x * 256 + threadIdx.x;
    if (i < n4){
        float4 v = ((const float4*)in)[i];
        ushort4 o = { f2bf(v.x), f2bf(v.y), f2bf(v.z), f2bf(v.w) };
        ((ushort4*)outp)[i] = o;
    }
}

// ---------------------------------------------------------------- aggregation (device helper)
// Pull-CSR aggregate of 8 nodes per wave into swizzled fp32 LDS tile xT, from a
// bf16 node table (256 B/row). 32 lanes per node (ushort4 = 4 feats each),
// 2 nodes per wave. Index-cache: lane l loads slot[o+l] + dinv coalesced; the
// gather loop gets (s,d) via __shfl. Groups of 8 load into named registers
// FIRST (8 loads in flight), then convert+FMA. Lanes past rem: idx=0, d=0 ->
// read row 0 (in-bounds, L1-hot), add 0.
// xT word(k,r) = k*32 + 4*((r>>2)^((k>>2)&7)) + (r&3); k>>2 == l here.
__device__ __forceinline__ void aggregate_tile_bf(const unsigned short* __restrict__ Xh,
        const uint32_t* __restrict__ offs, const uint32_t* __restrict__ cnt,
        const uint32_t* __restrict__ slot, const float* __restrict__ dinv,
        float* __restrict__ xT, int r0, int tid){
    int wid = tid >> 6, lane = tid & 63;
    int h = lane >> 5, l = lane & 31;
    const ushort4* X4 = (const ushort4*)Xh;   // 32 ushort4 per 128-feat row
    #pragma unroll 1
    for (int i = 0; i < 4; i++){
        int r = wid * 8 + 2 * i + h;
        int g = r0 + r;
        uint32_t o = offs[g], c = cnt[g];
        float ax = 0.f, ay = 0.f, az = 0.f, aw = 0.f;
        #pragma unroll 1
        for (uint32_t base = 0; base < c; base += 32){
            int rem = (int)(c - base); if (rem > 32) rem = 32;
            uint32_t idx = 0u; float ds = 0.f;
            if (l < rem){
                idx = slot[o + base + (uint32_t)l];
                ds = dinv[idx];
            }
            int groups = (rem + 7) >> 3;
            #pragma unroll 1
            for (int gq = 0; gq < groups; gq++){
                int eb = gq * 8;
                ushort4 v[8]; float d[8];
                #pragma unroll
                for (int j = 0; j < 8; j++){
                    uint32_t s = (uint32_t)__shfl((int)idx, eb + j, 32);
                    d[j] = __shfl(ds, eb + j, 32);
                    v[j] = X4[(size_t)s * 32 + l];
                }
                #pragma unroll
                for (int j = 0; j < 8; j++){
                    ax += d[j] * bf2f(v[j].x);
                    ay += d[j] * bf2f(v[j].y);
                    az += d[j] * bf2f(v[j].z);
                    aw += d[j] * bf2f(v[j].w);
                }
            }
        }
        float dd = dinv[g];
        ushort4 sv = X4[(size_t)g * 32 + l];
        int sw = (((r >> 2) ^ (l & 7)) << 2) + (r & 3);
        xT[(4 * l + 0) * 32 + sw] = dd * (ax + dd * bf2f(sv.x));
        xT[(4 * l + 1) * 32 + sw] = dd * (ay + dd * bf2f(sv.y));
        xT[(4 * l + 2) * 32 + sw] = dd * (az + dd * bf2f(sv.z));
        xT[(4 * l + 3) * 32 + sw] = dd * (aw + dd * bf2f(sv.w));
    }
}

// ---------------------------------------------------------------- fused layer 1
// A_bf16 = relu( (A_hat x_bf16) @ W1 + b1 ), 32 nodes/block, 256 threads, LDS = 32 KiB.
__global__ __launch_bounds__(256) void fused_layer1(const unsigned short* __restrict__ Xh,
        const uint32_t* __restrict__ offs, const uint32_t* __restrict__ cnt,
        const uint32_t* __restrict__ slot, const float* __restrict__ dinv,
        const float* __restrict__ W, const float* __restrict__ bias,
        unsigned short* __restrict__ OUT){
    __shared__ float Wl[32 * 128];    // 16 KiB (one 32-row K-chunk of W)
    __shared__ float xT[128 * 32];    // 16 KiB, swizzled [k][r]
    int tid = threadIdx.x;
    int r0 = blockIdx.x * 32;

    aggregate_tile_bf(Xh, offs, cnt, slot, dinv, xT, r0, tid);

    const float4* W4 = (const float4*)W;    // [128][128] row-major -> 32 float4/row
    float4* Wl4 = (float4*)Wl;
    const float4* xT4 = (const float4*)xT;
    int cg = tid & 31, rg = tid >> 5;
    float4 acc0 = {0,0,0,0}, acc1 = {0,0,0,0}, acc2 = {0,0,0,0}, acc3 = {0,0,0,0};

    #pragma unroll 1
    for (int chunk = 0; chunk < 4; chunk++){
        __syncthreads();                    // xT ready (1st) / prev chunk consumed (rest)
        for (int j = tid; j < 1024; j += 256) Wl4[j] = W4[chunk * 1024 + j];
        __syncthreads();
        #pragma unroll 8
        for (int kk = 0; kk < 32; kk++){
            int k = chunk * 32 + kk;
            float4 w  = Wl4[kk * 32 + cg];
            float4 xv = xT4[k * 8 + (rg ^ ((k >> 2) & 7))];
            acc0.x += xv.x * w.x; acc0.y += xv.x * w.y; acc0.z += xv.x * w.z; acc0.w += xv.x * w.w;
            acc1.x += xv.y * w.x; acc1.y += xv.y * w.y; acc1.z += xv.y * w.z; acc1.w += xv.y * w.w;
            acc2.x += xv.z * w.x; acc2.y += xv.z * w.y; acc2.z += xv.z * w.z; acc2.w += xv.z * w.w;
            acc3.x += xv.w * w.x; acc3.y += xv.w * w.y; acc3.z += xv.w * w.z; acc3.w += xv.w * w.w;
        }
    }

    float4 b = ((const float4*)bias)[cg];
    ushort4* O4 = (ushort4*)OUT;            // 128 bf16/row = 32 ushort4
    int rowbase = r0 + rg * 4;
    ushort4 o0 = { f2bf(fmaxf(acc0.x + b.x, 0.f)), f2bf(fmaxf(acc0.y + b.y, 0.f)),
                   f2bf(fmaxf(acc0.z + b.z, 0.f)), f2bf(fmaxf(acc0.w + b.w, 0.f)) };
    ushort4 o1 = { f2bf(fmaxf(acc1.x + b.x, 0.f)), f2bf(fmaxf(acc1.y + b.y, 0.f)),
                   f2bf(fmaxf(acc1.z + b.z, 0.f)), f2bf(fmaxf(acc1.w + b.w, 0.f)) };
    ushort4 o2 = { f2bf(fmaxf(acc2.x + b.x, 0.f)), f2bf(fmaxf(acc2.y + b.y, 0.f)),
                   f2bf(fmaxf(acc2.z + b.z, 0.f)), f2bf(fmaxf(acc2.w + b.w, 0.f)) };
    ushort4 o3 = { f2bf(fmaxf(acc3.x + b.x, 0.f)), f2bf(fmaxf(acc3.y + b.y, 0.f)),
                   f2bf(fmaxf(acc3.z + b.z, 0.f)), f2bf(fmaxf(acc3.w + b.w, 0.f)) };
    O4[(size_t)(rowbase + 0) * 32 + cg] = o0;
    O4[(size_t)(rowbase + 1) * 32 + cg] = o1;
    O4[(size_t)(rowbase + 2) * 32 + cg] = o2;
    O4[(size_t)(rowbase + 3) * 32 + cg] = o3;
}

// ---------------------------------------------------------------- fused layer 2
// out = (A_hat A_bf16) @ W2 + b2, 32 nodes/block, 256 threads, LDS = 26 KiB.
__global__ __launch_bounds__(256) void fused_layer2(const unsigned short* __restrict__ Ah,
        const uint32_t* __restrict__ offs, const uint32_t* __restrict__ cnt,
        const uint32_t* __restrict__ slot, const float* __restrict__ dinv,
        const float* __restrict__ W, const float* __restrict__ bias,
        float* __restrict__ OUT){
    __shared__ float Wl[64 * 40];     // 10 KiB (one 64-row K-chunk of W2)
    __shared__ float xT[128 * 32];    // 16 KiB, swizzled [k][r]
    int tid = threadIdx.x;
    int r0 = blockIdx.x * 32;

    aggregate_tile_bf(Ah, offs, cnt, slot, dinv, xT, r0, tid);

    const float4* W4 = (const float4*)W;   // [128][40] -> 10 float4/row
    float4* Wl4 = (float4*)Wl;
    int r = tid >> 3, cw = tid & 7;        // 32 rows x 8 col-groups (5 cols each)
    int rhi = r >> 2, rlo = r & 3;
    float acc[5] = {0.f, 0.f, 0.f, 0.f, 0.f};

    #pragma unroll 1
    for (int chunk = 0; chunk < 2; chunk++){
        __syncthreads();
        for (int j = tid; j < 640; j += 256) Wl4[j] = W4[chunk * 640 + j];
        __syncthreads();
        #pragma unroll 8
        for (int kk = 0; kk < 64; kk++){
            int k = chunk * 64 + kk;
            float xv = xT[k * 32 + (((rhi ^ ((k >> 2) & 7)) << 2) + rlo)];
            #pragma unroll
            for (int j = 0; j < 5; j++)
                acc[j] += xv * Wl[kk * 40 + 5 * cw + j];
        }
    }
    int g = r0 + r;
    #pragma unroll
    for (int j = 0; j < 5; j++)
        OUT[(size_t)g * 40 + 5 * cw + j] = acc[j] + bias[5 * cw + j];
}

// ---------------------------------------------------------------- launch
extern "C" void kernel_launch(void* const* d_in, const int* in_sizes, int n_in,
                              void* d_out, int out_size, void* d_ws, size_t ws_size,
                              hipStream_t stream) {
    const float* x   = (const float*)d_in[0];
    const int*   ei  = (const int*)d_in[1];      // int32 (harness converts integer inputs)
    const float* W1  = (const float*)d_in[2];
    const float* b1  = (const float*)d_in[3];
    const float* W2  = (const float*)d_in[4];
    const float* b2  = (const float*)d_in[5];
    float*       out = (float*)d_out;

    const int N = N_NODES;
    const int E = in_sizes[1] / 2;
    const int* src = ei;
    const int* dst = ei + E;

    // workspace carve-up (512B-aligned). ~57 MiB total.
    char* ws = (char*)d_ws;
    size_t o = 0;
    auto alloc = [&](size_t bytes) -> char* {
        char* p = ws + o;
        o += (bytes + 511) & ~(size_t)511;
        return p;
    };
    uint32_t*       cnt   = (uint32_t*)alloc((size_t)N * 4);
    uint32_t*       offs  = (uint32_t*)alloc((size_t)N * 4);
    uint32_t*       cur   = (uint32_t*)alloc((size_t)N * 4);
    uint32_t*       bsum  = (uint32_t*)alloc(1024 * 4);
    uint32_t*       boff  = (uint32_t*)alloc(1024 * 4);
    uint32_t*       bsum2 = (uint32_t*)alloc(512);
    uint32_t*       slot  = (uint32_t*)alloc((size_t)E * 4);
    float*          dinv  = (float*)alloc((size_t)N * 4);
    unsigned short* Xh    = (unsigned short*)alloc((size_t)N * 128 * 2);  // bf16 x
    unsigned short* Ah    = (unsigned short*)alloc((size_t)N * 128 * 2);  // bf16 layer-1 act

    const int zspan = (int)(((char*)cur - (char*)cnt) / 4) + N;  // cnt..cur inclusive
    const int nblk_edges = (E + 255) / 256;       // 2500
    const int nblk_scan  = (N + 1023) / 1024;     // 98
    const int n4 = N * 128 / 4;                   // float4 count for conversion

    // --- graph structure + bf16 conversion (independent; conversion overlaps CSR chain) ---
    zero_u32<<<(zspan + 255) / 256, 256, 0, stream>>>(cnt, zspan);
    to_bf16<<<(n4 + 255) / 256, 256, 0, stream>>>(x, Xh, n4);
    count_dst<<<nblk_edges, 256, 0, stream>>>(dst, cnt, E);
    scan_blocks<<<nblk_scan, 256, 0, stream>>>(cnt, offs, bsum, N);
    scan_blocks<<<1, 256, 0, stream>>>(bsum, boff, bsum2, nblk_scan);
    add_boff_dinv<<<nblk_scan, 256, 0, stream>>>(offs, boff, cnt, dinv, N);
    fill_csr<<<nblk_edges, 256, 0, stream>>>(src, dst, offs, cur, slot, E);

    // --- layer 1: Ah = bf16( relu( (A_hat x) W1 + b1 ) ) ---
    fused_layer1<<<N / 32, 256, 0, stream>>>(Xh, offs, cnt, slot, dinv, W1, b1, Ah);

    // --- layer 2: out = (A_hat Ah) W2 + b2 ---
    fused_layer2<<<N / 32, 256, 0, stream>>>(Ah, offs, cnt, slot, dinv, W2, b2, out);
}